// Round 1
// baseline (2934.446 us; speedup 1.0000x reference)
//
#include <hip/hip_runtime.h>
#include <hip/hip_bf16.h>

// Problem constants (fixed by the reference's setup_inputs).
#define N_USERS   40000
#define N_ITEMS   16384
#define BATCHN    64
#define LAMBDA_REG 500.0f
#define MAXIT     30
#define TOL2      (1e-6f * 1e-6f)
#define SS        16   // floats between per-batch scalar slots (64B -> distinct cache lines for atomics)

// ---------------------------------------------------------------------------
// Preprocessing: counting-sort COO into CSR (by row) and CSC (by col).
// ---------------------------------------------------------------------------
__global__ void k_count(const int* __restrict__ rows, const int* __restrict__ cols,
                        int* __restrict__ rowcnt, int* __restrict__ colcnt, int nnz) {
    int i = blockIdx.x * blockDim.x + threadIdx.x;
    if (i < nnz) {
        atomicAdd(&rowcnt[rows[i]], 1);
        atomicAdd(&colcnt[cols[i]], 1);
    }
}

// Single-block exclusive scan (n <= ~64K via chunking). Writes ptr[0..n] and cur[0..n-1]=ptr.
__global__ void k_scan(const int* __restrict__ cnt, int n,
                       int* __restrict__ ptr, int* __restrict__ cur) {
    const int T = 1024;
    __shared__ int sums[T];
    int t = threadIdx.x;
    int chunk = (n + T - 1) / T;
    int lo = t * chunk, hi = min(n, lo + chunk);
    int s = 0;
    for (int i = lo; i < hi; ++i) s += cnt[i];
    sums[t] = s;
    __syncthreads();
    for (int off = 1; off < T; off <<= 1) {
        int v = (t >= off) ? sums[t - off] : 0;
        __syncthreads();
        sums[t] += v;
        __syncthreads();
    }
    int run = (t == 0) ? 0 : sums[t - 1];
    for (int i = lo; i < hi; ++i) {
        int c = cnt[i];
        ptr[i] = run;
        cur[i] = run;
        run += c;
    }
    if (t == 0) ptr[n] = sums[T - 1];
}

// Scatter entries into CSR (packed {col, val}) and CSC (packed {row, val}).
__global__ void k_scatter(const int* __restrict__ rows, const int* __restrict__ cols,
                          const float* __restrict__ vals,
                          int* __restrict__ row_cur, int* __restrict__ col_cur,
                          int2* __restrict__ csr, int2* __restrict__ csc, int nnz) {
    int i = blockIdx.x * blockDim.x + threadIdx.x;
    if (i < nnz) {
        int r = rows[i], c = cols[i];
        int vb = __float_as_int(vals[i]);
        int p = atomicAdd(&row_cur[r], 1);
        csr[p] = make_int2(c, vb);
        int q = atomicAdd(&col_cur[c], 1);
        csc[q] = make_int2(r, vb);
    }
}

// ---------------------------------------------------------------------------
// Transposes between (batch, items) and (items, batch) layouts. 64x64 LDS tiles.
// ---------------------------------------------------------------------------
__global__ void k_transpose_in(const float* __restrict__ in, float* __restrict__ out) {
    __shared__ float tile[64][65];
    int i0 = blockIdx.x * 64;
    int lane = threadIdx.x & 63;
    int g = threadIdx.x >> 6;  // 0..3
    for (int r = 0; r < 16; ++r) {
        int bb = g + 4 * r;
        tile[lane][bb] = in[bb * N_ITEMS + i0 + lane];  // coalesced over lane=item
    }
    __syncthreads();
    for (int r = 0; r < 16; ++r) {
        int ii = g + 4 * r;
        out[(i0 + ii) * 64 + lane] = tile[ii][lane];    // coalesced over lane=batch
    }
}

__global__ void k_transpose_out(const float* __restrict__ X, float* __restrict__ out) {
    __shared__ float tile[64][65];
    int i0 = blockIdx.x * 64;
    int lane = threadIdx.x & 63;
    int g = threadIdx.x >> 6;
    for (int r = 0; r < 16; ++r) {
        int ii = g + 4 * r;
        tile[ii][lane] = X[(i0 + ii) * 64 + lane];      // coalesced over lane=batch
    }
    __syncthreads();
    for (int r = 0; r < 16; ++r) {
        int bb = g + 4 * r;
        out[bb * N_ITEMS + i0 + lane] = tile[lane][bb]; // coalesced over lane=item
    }
}

// ---------------------------------------------------------------------------
// SpMM pass 1: tmp[r][b] = sum_{e in row r} val_e * V[col_e][b]. 1 wave per row.
// ---------------------------------------------------------------------------
__global__ void k_spmm1(const int* __restrict__ row_ptr, const int2* __restrict__ csr,
                        const float* __restrict__ V, float* __restrict__ tmp,
                        const int* __restrict__ done, int check_done) {
    if (check_done && *done) return;
    int wave = (blockIdx.x * blockDim.x + threadIdx.x) >> 6;
    int lane = threadIdx.x & 63;
    if (wave >= N_USERS) return;
    int beg = row_ptr[wave], end = row_ptr[wave + 1];
    float acc = 0.f;
    for (int p = beg; p < end; ++p) {
        int2 e = csr[p];
        acc += __int_as_float(e.y) * V[e.x * 64 + lane];
    }
    tmp[wave * 64 + lane] = acc;
}

// ---------------------------------------------------------------------------
// SpMM pass 2 (+ optional lambda*P and dot(P,AP) fused):
// out[c][b] = sum_{e in col c} val_e * tmp[row_e][b]  (+ lambda*P[c][b])
// ---------------------------------------------------------------------------
__global__ void k_spmm2(const int* __restrict__ col_ptr, const int2* __restrict__ csc,
                        const float* __restrict__ tmp, const float* __restrict__ P,
                        float* __restrict__ out, float* __restrict__ dot,
                        int with_dot, const int* __restrict__ done, int check_done) {
    if (check_done && *done) return;
    int lane = threadIdx.x & 63;
    int wid = threadIdx.x >> 6;
    int gw = blockIdx.x * 4 + wid;
    int nw = gridDim.x * 4;
    float dpart = 0.f;
    for (int col = gw; col < N_ITEMS; col += nw) {
        int beg = col_ptr[col], end = col_ptr[col + 1];
        float acc = 0.f;
        for (int p = beg; p < end; ++p) {
            int2 e = csc[p];
            acc += __int_as_float(e.y) * tmp[e.x * 64 + lane];
        }
        if (with_dot) {
            float pv = P[col * 64 + lane];
            acc += LAMBDA_REG * pv;
            dpart += acc * pv;
        }
        out[col * 64 + lane] = acc;
    }
    if (with_dot) {
        __shared__ float sred[256];
        sred[threadIdx.x] = dpart;
        __syncthreads();
        if (threadIdx.x < 64) {
            float s = sred[threadIdx.x] + sred[threadIdx.x + 64] +
                      sred[threadIdx.x + 128] + sred[threadIdx.x + 192];
            atomicAdd(&dot[threadIdx.x * SS], s);
        }
    }
}

// ---------------------------------------------------------------------------
// CG state kernels
// ---------------------------------------------------------------------------
// X = 0, P = y (R aliases y), Rs0[b] = sum_i y[i][b]^2
__global__ void k_init(const float* __restrict__ y, float* __restrict__ X,
                       float* __restrict__ P, float* __restrict__ Rs0) {
    int idx0 = blockIdx.x * blockDim.x + threadIdx.x;
    int stride = gridDim.x * blockDim.x;  // multiple of 64
    float acc = 0.f;
    for (int i = idx0; i < N_ITEMS * 64; i += stride) {
        float v = y[i];
        X[i] = 0.f;
        P[i] = v;
        acc += v * v;
    }
    __shared__ float sred[256];
    sred[threadIdx.x] = acc;
    __syncthreads();
    if (threadIdx.x < 64) {
        float s = sred[threadIdx.x] + sred[threadIdx.x + 64] +
                  sred[threadIdx.x + 128] + sred[threadIdx.x + 192];
        atomicAdd(&Rs0[threadIdx.x * SS], s);
    }
}

// alpha = Rs_old/(dot+1e-12); X += alpha P; R -= alpha AP; Rs_new[b] += R^2
__global__ void k_update1(float* __restrict__ X, float* __restrict__ R,
                          const float* __restrict__ P, const float* __restrict__ AP,
                          const float* __restrict__ Rs_old, const float* __restrict__ dot,
                          float* __restrict__ Rs_new, const int* __restrict__ done) {
    if (*done) return;
    int lane = threadIdx.x & 63;
    float alpha = Rs_old[lane * SS] / (dot[lane * SS] + 1e-12f);
    int idx0 = blockIdx.x * blockDim.x + threadIdx.x;
    int stride = gridDim.x * blockDim.x;
    float acc = 0.f;
    for (int i = idx0; i < N_ITEMS * 64; i += stride) {
        X[i] += alpha * P[i];
        float r = R[i] - alpha * AP[i];
        R[i] = r;
        acc += r * r;
    }
    __shared__ float sred[256];
    sred[threadIdx.x] = acc;
    __syncthreads();
    if (threadIdx.x < 64) {
        float s = sred[threadIdx.x] + sred[threadIdx.x + 64] +
                  sred[threadIdx.x + 128] + sred[threadIdx.x + 192];
        atomicAdd(&Rs_new[threadIdx.x * SS], s);
    }
}

// conv check: max_b Rs_new < TOL^2 -> done=1
__global__ void k_check(const float* __restrict__ Rs_new, int* __restrict__ done) {
    int t = threadIdx.x;  // 64 threads
    float v = Rs_new[t * SS];
    for (int off = 32; off; off >>= 1) v = fmaxf(v, __shfl_down(v, off));
    if (t == 0 && v < TOL2) *done = 1;
}

// beta = Rs_new/(Rs_old+1e-12); P = R + beta P
__global__ void k_update2(float* __restrict__ P, const float* __restrict__ R,
                          const float* __restrict__ Rs_new, const float* __restrict__ Rs_old,
                          const int* __restrict__ done) {
    if (*done) return;
    int lane = threadIdx.x & 63;
    float beta = Rs_new[lane * SS] / (Rs_old[lane * SS] + 1e-12f);
    int idx0 = blockIdx.x * blockDim.x + threadIdx.x;
    int stride = gridDim.x * blockDim.x;
    for (int i = idx0; i < N_ITEMS * 64; i += stride) {
        P[i] = R[i] + beta * P[i];
    }
}

// ---------------------------------------------------------------------------
extern "C" void kernel_launch(void* const* d_in, const int* in_sizes, int n_in,
                              void* d_out, int out_size, void* d_ws, size_t ws_size,
                              hipStream_t stream) {
    const float* Xb   = (const float*)d_in[0];  // (64, 16384)
    const int*   rows = (const int*)d_in[1];
    const int*   cols = (const int*)d_in[2];
    const float* vals = (const float*)d_in[3];
    int nnz = in_sizes[1];

    char* ws = (char*)d_ws;
    size_t o = 0;
    auto alloc = [&](size_t bytes) -> char* {
        char* p = ws + o;
        o = (o + bytes + 255) & ~(size_t)255;
        return p;
    };

    // --- zero region (one memset): rowcnt, colcnt, Rs slots, dot slots, done ---
    const size_t ROWCNT_B = (size_t)N_USERS * 4;            // 160000 (mult of 256)
    const size_t COLCNT_B = (size_t)N_ITEMS * 4;            // 65536
    const size_t RS_B     = (size_t)(MAXIT + 1) * 64 * SS * 4;  // 31 slots * 4KB
    const size_t DOT_B    = (size_t)MAXIT * 64 * SS * 4;        // 30 slots * 4KB
    const size_t DONE_B   = 256;
    const size_t ZERO_B   = ROWCNT_B + COLCNT_B + RS_B + DOT_B + DONE_B;
    char* zero_base = alloc(ZERO_B);
    int*   rowcnt = (int*)zero_base;
    int*   colcnt = (int*)(zero_base + ROWCNT_B);
    float* Rs_f   = (float*)(zero_base + ROWCNT_B + COLCNT_B);
    float* dot_f  = (float*)(zero_base + ROWCNT_B + COLCNT_B + RS_B);
    int*   done   = (int*)(zero_base + ROWCNT_B + COLCNT_B + RS_B + DOT_B);

    int*  row_ptr = (int*)alloc((size_t)(N_USERS + 1) * 4);
    int*  row_cur = (int*)alloc((size_t)N_USERS * 4);
    int*  col_ptr = (int*)alloc((size_t)(N_ITEMS + 1) * 4);
    int*  col_cur = (int*)alloc((size_t)N_ITEMS * 4);
    int2* csr     = (int2*)alloc((size_t)nnz * 8);
    int2* csc     = (int2*)alloc((size_t)nnz * 8);
    float* Xt  = (float*)alloc((size_t)N_ITEMS * 64 * 4);   // X_batch^T, (items, batch)
    float* tmp = (float*)alloc((size_t)N_USERS * 64 * 4);   // (users, batch)
    float* R   = (float*)alloc((size_t)N_ITEMS * 64 * 4);   // also holds y
    float* Xv  = (float*)alloc((size_t)N_ITEMS * 64 * 4);
    float* P   = (float*)alloc((size_t)N_ITEMS * 64 * 4);
    float* AP  = (float*)alloc((size_t)N_ITEMS * 64 * 4);
    (void)ws_size; (void)n_in; (void)out_size;

    hipMemsetAsync(zero_base, 0, ZERO_B, stream);

    int nb = (nnz + 255) / 256;
    k_count<<<nb, 256, 0, stream>>>(rows, cols, rowcnt, colcnt, nnz);
    k_scan<<<1, 1024, 0, stream>>>(rowcnt, N_USERS, row_ptr, row_cur);
    k_scan<<<1, 1024, 0, stream>>>(colcnt, N_ITEMS, col_ptr, col_cur);
    k_scatter<<<nb, 256, 0, stream>>>(rows, cols, vals, row_cur, col_cur, csr, csc, nnz);

    k_transpose_in<<<N_ITEMS / 64, 256, 0, stream>>>(Xb, Xt);

    // y = S_mm(X_batch^T): stored into R (R0 = P0 = y)
    k_spmm1<<<(N_USERS * 64) / 256, 256, 0, stream>>>(row_ptr, csr, Xt, tmp, done, 0);
    k_spmm2<<<1024, 256, 0, stream>>>(col_ptr, csc, tmp, nullptr, R, nullptr, 0, done, 0);
    k_init<<<512, 256, 0, stream>>>(R, Xv, P, Rs_f);  // Rs slot 0

    for (int t = 0; t < MAXIT; ++t) {
        float* Rs_old = Rs_f + (size_t)t * 64 * SS;
        float* Rs_new = Rs_f + (size_t)(t + 1) * 64 * SS;
        float* dot    = dot_f + (size_t)t * 64 * SS;
        k_spmm1<<<(N_USERS * 64) / 256, 256, 0, stream>>>(row_ptr, csr, P, tmp, done, 1);
        k_spmm2<<<1024, 256, 0, stream>>>(col_ptr, csc, tmp, P, AP, dot, 1, done, 1);
        k_update1<<<512, 256, 0, stream>>>(Xv, R, P, AP, Rs_old, dot, Rs_new, done);
        k_check<<<1, 64, 0, stream>>>(Rs_new, done);
        k_update2<<<512, 256, 0, stream>>>(P, R, Rs_new, Rs_old, done);
    }

    k_transpose_out<<<N_ITEMS / 64, 256, 0, stream>>>(Xv, (float*)d_out);
}

// Round 2
// 2358.476 us; speedup vs baseline: 1.2442x; 1.2442x over previous
//
#include <hip/hip_runtime.h>
#include <hip/hip_bf16.h>

// Problem constants (fixed by the reference's setup_inputs).
#define N_USERS   40000
#define N_ITEMS   16384
#define BATCHN    64
#define LAMBDA_REG 500.0f
#define MAXIT     30
#define TOL2      (1e-6f * 1e-6f)
#define SS        16   // floats between per-batch scalar slots (64B -> distinct cache lines for atomics)
#define NPASS     8    // filtered-scatter passes (locality windows)

// ---------------------------------------------------------------------------
// Preprocessing: counting-sort COO into CSR (by row) and CSC (by col).
// ---------------------------------------------------------------------------
__global__ void k_count(const int* __restrict__ rows, const int* __restrict__ cols,
                        int* __restrict__ rowcnt, int* __restrict__ colcnt, int nnz) {
    int i = blockIdx.x * blockDim.x + threadIdx.x;
    if (i < nnz) {
        atomicAdd(&rowcnt[rows[i]], 1);
        atomicAdd(&colcnt[cols[i]], 1);
    }
}

// Single-block exclusive scan (n <= ~64K via chunking). Writes ptr[0..n] and cur[0..n-1]=ptr.
__global__ void k_scan(const int* __restrict__ cnt, int n,
                       int* __restrict__ ptr, int* __restrict__ cur) {
    const int T = 1024;
    __shared__ int sums[T];
    int t = threadIdx.x;
    int chunk = (n + T - 1) / T;
    int lo = t * chunk, hi = min(n, lo + chunk);
    int s = 0;
    for (int i = lo; i < hi; ++i) s += cnt[i];
    sums[t] = s;
    __syncthreads();
    for (int off = 1; off < T; off <<= 1) {
        int v = (t >= off) ? sums[t - off] : 0;
        __syncthreads();
        sums[t] += v;
        __syncthreads();
    }
    int run = (t == 0) ? 0 : sums[t - 1];
    for (int i = lo; i < hi; ++i) {
        int c = cnt[i];
        ptr[i] = run;
        cur[i] = run;
        run += c;
    }
    if (t == 0) ptr[n] = sums[T - 1];
}

// Filtered scatter: only entries with row in [r0,r1) go to CSR, col in [c0,c1)
// to CSC. Destination windows are ~1MB -> writes coalesce in L2 (write-amp ~1
// instead of ~8 for full-random 8B scatter over 8MB).
__global__ void k_scatter_f(const int* __restrict__ rows, const int* __restrict__ cols,
                            const float* __restrict__ vals,
                            int* __restrict__ row_cur, int* __restrict__ col_cur,
                            int2* __restrict__ csr, int2* __restrict__ csc, int nnz,
                            int r0, int r1, int c0, int c1) {
    int i = blockIdx.x * blockDim.x + threadIdx.x;
    if (i >= nnz) return;
    int r = rows[i], c = cols[i];
    bool mr = (r >= r0) & (r < r1);
    bool mc = (c >= c0) & (c < c1);
    if (!mr && !mc) return;
    int vb = __float_as_int(vals[i]);
    if (mr) { int p = atomicAdd(&row_cur[r], 1); csr[p] = make_int2(c, vb); }
    if (mc) { int q = atomicAdd(&col_cur[c], 1); csc[q] = make_int2(r, vb); }
}

// ---------------------------------------------------------------------------
// Transposes between (batch, items) and (items, batch) layouts. 64x64 LDS tiles.
// ---------------------------------------------------------------------------
__global__ void k_transpose_in(const float* __restrict__ in, float* __restrict__ out) {
    __shared__ float tile[64][65];
    int i0 = blockIdx.x * 64;
    int lane = threadIdx.x & 63;
    int g = threadIdx.x >> 6;  // 0..3
    for (int r = 0; r < 16; ++r) {
        int bb = g + 4 * r;
        tile[lane][bb] = in[bb * N_ITEMS + i0 + lane];  // coalesced over lane=item
    }
    __syncthreads();
    for (int r = 0; r < 16; ++r) {
        int ii = g + 4 * r;
        out[(i0 + ii) * 64 + lane] = tile[ii][lane];    // coalesced over lane=batch
    }
}

__global__ void k_transpose_out(const float* __restrict__ X, float* __restrict__ out) {
    __shared__ float tile[64][65];
    int i0 = blockIdx.x * 64;
    int lane = threadIdx.x & 63;
    int g = threadIdx.x >> 6;
    for (int r = 0; r < 16; ++r) {
        int ii = g + 4 * r;
        tile[ii][lane] = X[(i0 + ii) * 64 + lane];      // coalesced over lane=batch
    }
    __syncthreads();
    for (int r = 0; r < 16; ++r) {
        int bb = g + 4 * r;
        out[bb * N_ITEMS + i0 + lane] = tile[lane][bb]; // coalesced over lane=item
    }
}

// ---------------------------------------------------------------------------
// SpMM pass 1: tmp[r][b] = sum_{e in row r} val_e * V[col_e][b]. 1 wave per row.
// Unrolled x4 so 4 independent 256B gathers are in flight per wave.
// ---------------------------------------------------------------------------
__global__ void k_spmm1(const int* __restrict__ row_ptr, const int2* __restrict__ csr,
                        const float* __restrict__ V, float* __restrict__ tmp,
                        const int* __restrict__ done, int check_done) {
    if (check_done && *done) return;
    int wave = (blockIdx.x * blockDim.x + threadIdx.x) >> 6;
    int lane = threadIdx.x & 63;
    if (wave >= N_USERS) return;
    int beg = row_ptr[wave], end = row_ptr[wave + 1];
    float acc = 0.f;
    int p = beg;
    for (; p + 4 <= end; p += 4) {
        int2 e0 = csr[p], e1 = csr[p + 1], e2 = csr[p + 2], e3 = csr[p + 3];
        float g0 = V[e0.x * 64 + lane];
        float g1 = V[e1.x * 64 + lane];
        float g2 = V[e2.x * 64 + lane];
        float g3 = V[e3.x * 64 + lane];
        acc += __int_as_float(e0.y) * g0;
        acc += __int_as_float(e1.y) * g1;
        acc += __int_as_float(e2.y) * g2;
        acc += __int_as_float(e3.y) * g3;
    }
    for (; p < end; ++p) {
        int2 e = csr[p];
        acc += __int_as_float(e.y) * V[e.x * 64 + lane];
    }
    tmp[wave * 64 + lane] = acc;
}

// ---------------------------------------------------------------------------
// SpMM pass 2 (+ optional lambda*P and dot(P,AP) fused). One wave per column.
// out[c][b] = sum_{e in col c} val_e * tmp[row_e][b]  (+ lambda*P[c][b])
// ---------------------------------------------------------------------------
__global__ void k_spmm2(const int* __restrict__ col_ptr, const int2* __restrict__ csc,
                        const float* __restrict__ tmp, const float* __restrict__ P,
                        float* __restrict__ out, float* __restrict__ dot,
                        int with_dot, const int* __restrict__ done, int check_done) {
    if (check_done && *done) return;
    int lane = threadIdx.x & 63;
    int col = blockIdx.x * 4 + (threadIdx.x >> 6);
    int beg = col_ptr[col], end = col_ptr[col + 1];
    float acc = 0.f;
    int p = beg;
    for (; p + 4 <= end; p += 4) {
        int2 e0 = csc[p], e1 = csc[p + 1], e2 = csc[p + 2], e3 = csc[p + 3];
        float g0 = tmp[e0.x * 64 + lane];
        float g1 = tmp[e1.x * 64 + lane];
        float g2 = tmp[e2.x * 64 + lane];
        float g3 = tmp[e3.x * 64 + lane];
        acc += __int_as_float(e0.y) * g0;
        acc += __int_as_float(e1.y) * g1;
        acc += __int_as_float(e2.y) * g2;
        acc += __int_as_float(e3.y) * g3;
    }
    for (; p < end; ++p) {
        int2 e = csc[p];
        acc += __int_as_float(e.y) * tmp[e.x * 64 + lane];
    }
    float dpart = 0.f;
    if (with_dot) {
        float pv = P[col * 64 + lane];
        acc += LAMBDA_REG * pv;
        dpart = acc * pv;
    }
    out[col * 64 + lane] = acc;
    if (with_dot) {
        __shared__ float sred[256];
        sred[threadIdx.x] = dpart;
        __syncthreads();
        if (threadIdx.x < 64) {
            float s = sred[threadIdx.x] + sred[threadIdx.x + 64] +
                      sred[threadIdx.x + 128] + sred[threadIdx.x + 192];
            atomicAdd(&dot[threadIdx.x * SS], s);
        }
    }
}

// ---------------------------------------------------------------------------
// CG state kernels
// ---------------------------------------------------------------------------
// X = 0, P = y (R aliases y), Rs0[b] = sum_i y[i][b]^2
__global__ void k_init(const float* __restrict__ y, float* __restrict__ X,
                       float* __restrict__ P, float* __restrict__ Rs0) {
    int idx0 = blockIdx.x * blockDim.x + threadIdx.x;
    int stride = gridDim.x * blockDim.x;  // multiple of 64
    float acc = 0.f;
    for (int i = idx0; i < N_ITEMS * 64; i += stride) {
        float v = y[i];
        X[i] = 0.f;
        P[i] = v;
        acc += v * v;
    }
    __shared__ float sred[256];
    sred[threadIdx.x] = acc;
    __syncthreads();
    if (threadIdx.x < 64) {
        float s = sred[threadIdx.x] + sred[threadIdx.x + 64] +
                  sred[threadIdx.x + 128] + sred[threadIdx.x + 192];
        atomicAdd(&Rs0[threadIdx.x * SS], s);
    }
}

// alpha = Rs_old/(dot+1e-12); X += alpha P; R -= alpha AP; Rs_new[b] += R^2.
// Last block (device-scope counter) also does the convergence check (replaces
// the separate k_check launch): max_b Rs_new < TOL^2 -> done=1.
__global__ void k_update1(float* __restrict__ X, float* __restrict__ R,
                          const float* __restrict__ P, const float* __restrict__ AP,
                          const float* __restrict__ Rs_old, const float* __restrict__ dot,
                          float* __restrict__ Rs_new, int* __restrict__ counter,
                          int* __restrict__ done) {
    if (*done) return;
    int lane = threadIdx.x & 63;
    float alpha = Rs_old[lane * SS] / (dot[lane * SS] + 1e-12f);
    int idx0 = blockIdx.x * blockDim.x + threadIdx.x;
    int stride = gridDim.x * blockDim.x;
    float acc = 0.f;
    for (int i = idx0; i < N_ITEMS * 64; i += stride) {
        X[i] += alpha * P[i];
        float r = R[i] - alpha * AP[i];
        R[i] = r;
        acc += r * r;
    }
    __shared__ float sred[256];
    sred[threadIdx.x] = acc;
    __syncthreads();
    if (threadIdx.x < 64) {
        float s = sred[threadIdx.x] + sred[threadIdx.x + 64] +
                  sred[threadIdx.x + 128] + sred[threadIdx.x + 192];
        atomicAdd(&Rs_new[threadIdx.x * SS], s);
    }
    __threadfence();
    __shared__ int lastf;
    if (threadIdx.x == 0) lastf = (atomicAdd(counter, 1) == (int)gridDim.x - 1);
    __syncthreads();
    if (lastf && threadIdx.x < 64) {
        // atomic read-back: coherent across XCDs (plain load could hit stale L2)
        float v = atomicAdd(&Rs_new[threadIdx.x * SS], 0.0f);
        for (int off = 32; off; off >>= 1) v = fmaxf(v, __shfl_down(v, off));
        if (threadIdx.x == 0 && v < TOL2) *done = 1;  // visible to later kernels
    }
}

// beta = Rs_new/(Rs_old+1e-12); P = R + beta P
__global__ void k_update2(float* __restrict__ P, const float* __restrict__ R,
                          const float* __restrict__ Rs_new, const float* __restrict__ Rs_old,
                          const int* __restrict__ done) {
    if (*done) return;
    int lane = threadIdx.x & 63;
    float beta = Rs_new[lane * SS] / (Rs_old[lane * SS] + 1e-12f);
    int idx0 = blockIdx.x * blockDim.x + threadIdx.x;
    int stride = gridDim.x * blockDim.x;
    for (int i = idx0; i < N_ITEMS * 64; i += stride) {
        P[i] = R[i] + beta * P[i];
    }
}

// ---------------------------------------------------------------------------
extern "C" void kernel_launch(void* const* d_in, const int* in_sizes, int n_in,
                              void* d_out, int out_size, void* d_ws, size_t ws_size,
                              hipStream_t stream) {
    const float* Xb   = (const float*)d_in[0];  // (64, 16384)
    const int*   rows = (const int*)d_in[1];
    const int*   cols = (const int*)d_in[2];
    const float* vals = (const float*)d_in[3];
    int nnz = in_sizes[1];

    char* ws = (char*)d_ws;
    size_t o = 0;
    auto alloc = [&](size_t bytes) -> char* {
        char* p = ws + o;
        o = (o + bytes + 255) & ~(size_t)255;
        return p;
    };

    // --- zero region (one memset): rowcnt, colcnt, Rs slots, dot slots, counters, done ---
    const size_t ROWCNT_B = (size_t)N_USERS * 4;                // 160000 (mult of 256)
    const size_t COLCNT_B = (size_t)N_ITEMS * 4;                // 65536
    const size_t RS_B     = (size_t)(MAXIT + 1) * 64 * SS * 4;  // 31 slots * 4KB
    const size_t DOT_B    = (size_t)MAXIT * 64 * SS * 4;        // 30 slots * 4KB
    const size_t CNT_B    = 256;                                // MAXIT counters
    const size_t DONE_B   = 256;
    const size_t ZERO_B   = ROWCNT_B + COLCNT_B + RS_B + DOT_B + CNT_B + DONE_B;
    char* zero_base = alloc(ZERO_B);
    int*   rowcnt   = (int*)zero_base;
    int*   colcnt   = (int*)(zero_base + ROWCNT_B);
    float* Rs_f     = (float*)(zero_base + ROWCNT_B + COLCNT_B);
    float* dot_f    = (float*)(zero_base + ROWCNT_B + COLCNT_B + RS_B);
    int*   counters = (int*)(zero_base + ROWCNT_B + COLCNT_B + RS_B + DOT_B);
    int*   done     = (int*)(zero_base + ROWCNT_B + COLCNT_B + RS_B + DOT_B + CNT_B);

    int*  row_ptr = (int*)alloc((size_t)(N_USERS + 1) * 4);
    int*  row_cur = (int*)alloc((size_t)N_USERS * 4);
    int*  col_ptr = (int*)alloc((size_t)(N_ITEMS + 1) * 4);
    int*  col_cur = (int*)alloc((size_t)N_ITEMS * 4);
    int2* csr     = (int2*)alloc((size_t)nnz * 8);
    int2* csc     = (int2*)alloc((size_t)nnz * 8);
    float* Xt  = (float*)alloc((size_t)N_ITEMS * 64 * 4);   // X_batch^T, (items, batch)
    float* tmp = (float*)alloc((size_t)N_USERS * 64 * 4);   // (users, batch)
    float* R   = (float*)alloc((size_t)N_ITEMS * 64 * 4);   // also holds y
    float* Xv  = (float*)alloc((size_t)N_ITEMS * 64 * 4);
    float* P   = (float*)alloc((size_t)N_ITEMS * 64 * 4);
    float* AP  = (float*)alloc((size_t)N_ITEMS * 64 * 4);
    (void)ws_size; (void)n_in; (void)out_size;

    hipMemsetAsync(zero_base, 0, ZERO_B, stream);

    int nb = (nnz + 255) / 256;
    k_count<<<nb, 256, 0, stream>>>(rows, cols, rowcnt, colcnt, nnz);
    k_scan<<<1, 1024, 0, stream>>>(rowcnt, N_USERS, row_ptr, row_cur);
    k_scan<<<1, 1024, 0, stream>>>(colcnt, N_ITEMS, col_ptr, col_cur);
    // Filtered scatter: NPASS passes, each with ~1MB destination windows.
    {
        const int RSPAN = (N_USERS + NPASS - 1) / NPASS;   // 5000
        const int CSPAN = (N_ITEMS + NPASS - 1) / NPASS;   // 2048
        for (int k = 0; k < NPASS; ++k) {
            k_scatter_f<<<nb, 256, 0, stream>>>(rows, cols, vals, row_cur, col_cur,
                                                csr, csc, nnz,
                                                k * RSPAN, (k + 1) * RSPAN,
                                                k * CSPAN, (k + 1) * CSPAN);
        }
    }

    k_transpose_in<<<N_ITEMS / 64, 256, 0, stream>>>(Xb, Xt);

    // y = S_mm(X_batch^T): stored into R (R0 = P0 = y)
    k_spmm1<<<(N_USERS * 64 + 255) / 256, 256, 0, stream>>>(row_ptr, csr, Xt, tmp, done, 0);
    k_spmm2<<<N_ITEMS / 4, 256, 0, stream>>>(col_ptr, csc, tmp, nullptr, R, nullptr, 0, done, 0);
    k_init<<<512, 256, 0, stream>>>(R, Xv, P, Rs_f);  // Rs slot 0

    for (int t = 0; t < MAXIT; ++t) {
        float* Rs_old = Rs_f + (size_t)t * 64 * SS;
        float* Rs_new = Rs_f + (size_t)(t + 1) * 64 * SS;
        float* dot    = dot_f + (size_t)t * 64 * SS;
        k_spmm1<<<(N_USERS * 64 + 255) / 256, 256, 0, stream>>>(row_ptr, csr, P, tmp, done, 1);
        k_spmm2<<<N_ITEMS / 4, 256, 0, stream>>>(col_ptr, csc, tmp, P, AP, dot, 1, done, 1);
        k_update1<<<512, 256, 0, stream>>>(Xv, R, P, AP, Rs_old, dot, Rs_new, counters + t, done);
        k_update2<<<512, 256, 0, stream>>>(P, R, Rs_new, Rs_old, done);
    }

    k_transpose_out<<<N_ITEMS / 64, 256, 0, stream>>>(Xv, (float*)d_out);
}